// Round 5
// baseline (157.337 us; speedup 1.0000x reference)
//
#include <hip/hip_runtime.h>

#define DI __device__ __forceinline__

typedef unsigned int uint32;
typedef unsigned short u16;
typedef __attribute__((ext_vector_type(8))) short s8v;   // 8 bf16 (4 VGPR)
typedef __attribute__((ext_vector_type(4))) float f4v;   // MFMA accumulator

DI float lrelu(float x, float s){ return x > 0.f ? x : s*x; }
DI u16 f2bu(float f){ uint32 u = __float_as_uint(f); return (u16)((u + 0x7FFFu + ((u>>16)&1u)) >> 16); }
DI float fastrcp(float x){ float r; asm("v_rcp_f32 %0, %1" : "=v"(r) : "v"(x)); return r; }

// branch-free gelu (erf via Abramowitz-Stegun 7.1.26, |eps|<=1.5e-7)
DI float gelu_f(float x){
  const float z = fabsf(x) * 0.70710678118654752f;
  const float t = fastrcp(1.f + 0.3275911f*z);
  float p = 1.061405429f;
  p = p*t - 1.453152027f;
  p = p*t + 1.421413741f;
  p = p*t - 0.284496736f;
  p = p*t + 0.254829592f;
  p = p*t;
  const float e = __expf(-z*z);
  float er = 1.f - p*e;
  er = copysignf(er, x);
  return 0.5f*x*(1.f + er);
}

DI f4v mfma16(s8v a, s8v b, f4v c){
  return __builtin_amdgcn_mfma_f32_16x16x32_bf16(a, b, c, 0, 0, 0);
}

constexpr int NNODE = 50;
constexpr int NT = 512;
constexpr int SCS = 134;     // sc row stride (f32)

// d_ws layout (u16 units):
constexpr int WS1  = 0;       // per-head [144][64]: rows 0..127 = W1^T head h, 128=es fold, 129=ed fold
constexpr int WS2  = 18432;   // [144][256]: rows 0..127 = W2^T, 128=es2 fold, 129=ed2 fold
constexpr int WSA1 = 55296;   // aw1^T [128][128]
constexpr int WSA2 = 71680;   // aw2^T [128][128]
constexpr int WSA3 = 88064;   // aw3^T padded [16][128] (rows 4..15 zero)
constexpr int WSTOT= 90112;   // * 2 bytes

__global__ __launch_bounds__(256)
void ac_prep(const float* __restrict__ w1, const float* __restrict__ as1, const float* __restrict__ ad1,
             const float* __restrict__ w2, const float* __restrict__ as2, const float* __restrict__ ad2,
             const float* __restrict__ aw1, const float* __restrict__ aw2, const float* __restrict__ aw3,
             u16* __restrict__ ws)
{
  const int T1 = 2*144*64, T2 = 144*256, T3 = 128*128;
  for (int t = blockIdx.x*blockDim.x + threadIdx.x; t < WSTOT; t += gridDim.x*blockDim.x){
    float v; int o;
    if (t < T1){
      int h = t / 9216, r = t - h*9216, n = r>>6, k = r&63;
      if (n < 128) v = w1[k*256 + h*128 + n];
      else if (n < 130){
        const float* av = ((n==129) ? ad1 : as1) + h*128;
        const float* wr = w1 + k*256 + h*128;
        float s = 0.f;
        for (int c=0;c<128;++c) s += wr[c]*av[c];
        v = s;
      } else v = 0.f;
      o = WS1 + h*9216 + n*64 + k;
    } else if (t < T1+T2){
      int j = t - T1, n = j>>8, k = j&255;
      if (n < 128) v = w2[k*128 + n];
      else if (n < 130){
        const float* av = (n==129) ? ad2 : as2;
        const float* wr = w2 + k*128;
        float s = 0.f;
        for (int c=0;c<128;++c) s += wr[c]*av[c];
        v = s;
      } else v = 0.f;
      o = WS2 + n*256 + k;
    } else if (t < T1+T2+T3){
      int j = t - T1 - T2, n = j>>7, k = j&127;
      v = aw1[k*128 + n];
      o = WSA1 + n*128 + k;
    } else if (t < T1+T2+2*T3){
      int j = t - T1 - T2 - T3, n = j>>7, k = j&127;
      v = aw2[k*128 + n];
      o = WSA2 + n*128 + k;
    } else {
      int j = t - T1 - T2 - 2*T3, m = j>>7, k = j&127;
      v = (m < 4) ? aw3[k*4 + m] : 0.f;
      o = WSA3 + m*128 + k;
    }
    ws[o] = f2bu(v);
  }
}

// LDS map (f32 words), total 18816 f = 75.26 KB -> 2 blocks/CU:
//  sc   [64][134] f32 @ 0          (C of every GEMM; score cols at 128/129)
//  Abuf bf16 16384 u16 @ 8576      (A2 [64][256] ; A3/A5 [64][128] first half, A4 second half)
//  As   bf16 4096 u16  @ 16768     (state tile [64][64]; dead after G1 -> overlay smalls)
//  geb4 [4][128] @ 16768 ; geb @ 17280 ; vh1 @ 17408

__global__ __launch_bounds__(NT)
__attribute__((amdgpu_waves_per_eu(4, 4)))
void ac_main(const float* __restrict__ state,
             const float* __restrict__ b1, const float* __restrict__ b2,
             const float* __restrict__ ab1, const float* __restrict__ ab2,
             const float* __restrict__ ab3,
             const float* __restrict__ vw1, const float* __restrict__ vb1,
             const float* __restrict__ vw2, const float* __restrict__ vb2,
             const float* __restrict__ vw3, const float* __restrict__ vb3,
             const u16* __restrict__ ws,
             float* __restrict__ out_mean, float* __restrict__ out_val)
{
  __shared__ __align__(16) float sm[18816];
  float* sc   = sm;
  u16*   pAb  = (u16*)(sm + 8576);
  u16*   pAb2 = pAb + 8192;
  u16*   pAs  = (u16*)(sm + 16768);
  float* geb4 = sm + 16768;   // overlays As (dead after G1 both heads)
  float* geb  = sm + 17280;
  float* vh1  = sm + 17408;

  const int tid = threadIdx.x, b = blockIdx.x;
  const int wid = tid>>6, l15 = tid&15, g = (tid>>4)&3;

  // ---- P0: pack state -> As bf16 [64][64], XOR-swizzled, rows 50..63 zero ----
  {
    const float4* xb4 = (const float4*)(state + (size_t)b * (NNODE*64));
    for (int t = tid; t < 800; t += NT){
      float4 v = xb4[t];
      int i = t>>4, k0 = (t&15)*4;
      ushort4 u;
      u.x = f2bu(v.x); u.y = f2bu(v.y); u.z = f2bu(v.z); u.w = f2bu(v.w);
      *(ushort4*)(pAs + i*64 + (k0 ^ ((i&7)<<3))) = u;
    }
    for (int t = tid; t < 224; t += NT){
      int i = 50 + (t>>4), k0 = (t&15)*4;
      *(ushort4*)(pAs + i*64 + (k0 ^ ((i&7)<<3))) = (ushort4){0,0,0,0};
    }
  }
  __syncthreads();

  // ---- G1 + attention1, per head ----
  for (int h=0; h<2; ++h){
    // G1 head h: C[64][130] -> sc (cols 0..127 features, 128=es, 129=ed)
    {
      s8v aS[4][2];
      #pragma unroll
      for (int mt=0;mt<4;++mt)
        #pragma unroll
        for (int ks=0;ks<2;++ks){
          int row = mt*16 + l15, c = ks*32 + g*8;
          aS[mt][ks] = *(const s8v*)(pAs + row*64 + (c ^ ((row&7)<<3)));
        }
      for (int nt = wid; nt < 9; nt += 8){
        f4v acc[4];
        #pragma unroll
        for (int mt=0;mt<4;++mt) acc[mt] = (f4v){0.f,0.f,0.f,0.f};
        #pragma unroll
        for (int ks=0;ks<2;++ks){
          s8v bf = *(const s8v*)(ws + WS1 + h*9216 + (nt*16 + l15)*64 + ks*32 + g*8);
          #pragma unroll
          for (int mt=0;mt<4;++mt) acc[mt] = mfma16(aS[mt][ks], bf, acc[mt]);
        }
        const int col = nt*16 + l15;
        if (col < 130){
          #pragma unroll
          for (int mt=0;mt<4;++mt){
            const int r0 = mt*16 + g*4;
            #pragma unroll
            for (int r=0;r<4;++r) sc[(r0+r)*SCS + col] = acc[mt][r];
          }
        }
      }
    }
    __syncthreads();

    // attention head h: 4 row-strips x 128 cols, rotating registers
    {
      const int q = tid>>7, j = tid&127, jj = h*128 + j;
      const int i0 = q*13, i1 = (i0+13 < NNODE) ? i0+13 : NNODE;
      const float bj = b1[jj];
      float pv  = (i0 > 0) ? sc[(i0-1)*SCS + j]   : 0.f;
      float cur = sc[i0*SCS + j];
      float esm = (i0 > 0) ? sc[(i0-1)*SCS + 128] : 0.f;
      float es0 = sc[i0*SCS + 128];
      #pragma unroll 4
      for (int i = i0; i < i1; ++i){
        const float nx  = (i < NNODE-1) ? sc[(i+1)*SCS + j]   : 0.f;
        const float esp = (i < NNODE-1) ? sc[(i+1)*SCS + 128] : 0.f;
        const float edi = sc[i*SCS + 129];
        const float wS = __expf(lrelu(es0 + edi, 0.2f));
        const float wL = (i > 0)       ? __expf(lrelu(esm + edi, 0.2f)) : 0.f;
        const float wR = (i < NNODE-1) ? __expf(lrelu(esp + edi, 0.2f)) : 0.f;
        const float rs = fastrcp(wL + wS + wR);
        const float agg = (wL*pv + wS*cur + wR*nx) * rs;
        const float v = gelu_f(agg + bj);
        pAb[i*256 + (jj ^ ((i&7)<<3))] = f2bu(v);
        pv = cur; cur = nx; esm = es0; es0 = esp;
      }
    }
    __syncthreads();
  }

  // ---- G2: C[64][130] = A2[64x256] x W2x^T -> sc ----
  for (int nt = wid; nt < 9; nt += 8){
    f4v acc[4];
    #pragma unroll
    for (int mt=0;mt<4;++mt) acc[mt] = (f4v){0.f,0.f,0.f,0.f};
    #pragma unroll
    for (int ks=0;ks<8;++ks){
      s8v bf = *(const s8v*)(ws + WS2 + (nt*16 + l15)*256 + ks*32 + g*8);
      #pragma unroll
      for (int mt=0;mt<4;++mt){
        const int row = mt*16 + l15, c = ks*32 + g*8;
        s8v a = *(const s8v*)(pAb + row*256 + (c ^ ((row&7)<<3)));
        acc[mt] = mfma16(a, bf, acc[mt]);
      }
    }
    const int col = nt*16 + l15;
    if (col < 130){
      #pragma unroll
      for (int mt=0;mt<4;++mt){
        const int r0 = mt*16 + g*4;
        #pragma unroll
        for (int r=0;r<4;++r) sc[(r0+r)*SCS + col] = acc[mt][r];
      }
    }
  }
  __syncthreads();

  // ---- attention2 + GELU -> A3 bf16 [64][128] ; pool partials ----
  {
    const int q = tid>>7, j = tid&127;
    const int i0 = q*13, i1 = (i0+13 < NNODE) ? i0+13 : NNODE;
    const float bj = b2[j];
    float ps = 0.f;
    float pv  = (i0 > 0) ? sc[(i0-1)*SCS + j]   : 0.f;
    float cur = sc[i0*SCS + j];
    float esm = (i0 > 0) ? sc[(i0-1)*SCS + 128] : 0.f;
    float es0 = sc[i0*SCS + 128];
    #pragma unroll 4
    for (int i = i0; i < i1; ++i){
      const float nx  = (i < NNODE-1) ? sc[(i+1)*SCS + j]   : 0.f;
      const float esp = (i < NNODE-1) ? sc[(i+1)*SCS + 128] : 0.f;
      const float edi = sc[i*SCS + 129];
      const float wS = __expf(lrelu(es0 + edi, 0.2f));
      const float wL = (i > 0)       ? __expf(lrelu(esm + edi, 0.2f)) : 0.f;
      const float wR = (i < NNODE-1) ? __expf(lrelu(esp + edi, 0.2f)) : 0.f;
      const float rs = fastrcp(wL + wS + wR);
      const float agg = (wL*pv + wS*cur + wR*nx) * rs;
      const float v = gelu_f(agg + bj);
      pAb[i*128 + (j ^ ((i&7)<<3))] = f2bu(v);
      ps += v;
      pv = cur; cur = nx; esm = es0; es0 = esp;
    }
    geb4[q*128 + j] = ps;
  }
  __syncthreads();

  // ---- G3: C = A3 x aw1^T ; fused lrelu+pack -> A4 ; geb finalize ----
  {
    const int nt = wid;
    f4v acc[4];
    #pragma unroll
    for (int mt=0;mt<4;++mt) acc[mt] = (f4v){0.f,0.f,0.f,0.f};
    #pragma unroll
    for (int ks=0;ks<4;++ks){
      s8v bf = *(const s8v*)(ws + WSA1 + (nt*16 + l15)*128 + ks*32 + g*8);
      #pragma unroll
      for (int mt=0;mt<4;++mt){
        const int row = mt*16 + l15, c = ks*32 + g*8;
        s8v a = *(const s8v*)(pAb + row*128 + (c ^ ((row&7)<<3)));
        acc[mt] = mfma16(a, bf, acc[mt]);
      }
    }
    const int col = nt*16 + l15;
    const float bj = ab1[col];
    #pragma unroll
    for (int mt=0;mt<4;++mt){
      #pragma unroll
      for (int r=0;r<4;++r){
        const int row = mt*16 + g*4 + r;
        const float v = lrelu(acc[mt][r] + bj, 0.01f);
        pAb2[row*128 + (col ^ ((row&7)<<3))] = f2bu(v);
      }
    }
    if (tid < 128)
      geb[tid] = (geb4[tid] + geb4[128+tid] + geb4[256+tid] + geb4[384+tid]) * 0.02f;
  }
  __syncthreads();

  // ---- G4: C = A4 x aw2^T ; fused lrelu(+ab2)+pack -> A5 (A3 region, dead) ----
  {
    const int nt = wid;
    f4v acc[4];
    #pragma unroll
    for (int mt=0;mt<4;++mt) acc[mt] = (f4v){0.f,0.f,0.f,0.f};
    #pragma unroll
    for (int ks=0;ks<4;++ks){
      s8v bf = *(const s8v*)(ws + WSA2 + (nt*16 + l15)*128 + ks*32 + g*8);
      #pragma unroll
      for (int mt=0;mt<4;++mt){
        const int row = mt*16 + l15, c = ks*32 + g*8;
        s8v a = *(const s8v*)(pAb2 + row*128 + (c ^ ((row&7)<<3)));
        acc[mt] = mfma16(a, bf, acc[mt]);
      }
    }
    const int col = nt*16 + l15;
    const float bj = ab2[col];
    #pragma unroll
    for (int mt=0;mt<4;++mt){
      #pragma unroll
      for (int r=0;r<4;++r){
        const int row = mt*16 + g*4 + r;
        const float v = lrelu(acc[mt][r] + bj, 0.01f);
        pAb[row*128 + (col ^ ((row&7)<<3))] = f2bu(v);
      }
    }
  }
  __syncthreads();

  // ---- G5: actor L3 via tiny MFMA (waves 0-3) ; value MLP (wave 4). No more barriers. ----
  if (wid < 4){
    const int mt = wid;
    f4v acc = (f4v){0.f,0.f,0.f,0.f};
    #pragma unroll
    for (int ks=0;ks<4;++ks){
      s8v bf = *(const s8v*)(ws + WSA3 + l15*128 + ks*32 + g*8);
      const int row = mt*16 + l15, c = ks*32 + g*8;
      s8v a = *(const s8v*)(pAb + row*128 + (c ^ ((row&7)<<3)));
      acc = mfma16(a, bf, acc);
    }
    if (l15 < 4){
      const float bj = ab3[l15];
      #pragma unroll
      for (int r=0;r<4;++r){
        const int row = mt*16 + g*4 + r;
        if (row < NNODE) out_mean[(size_t)b*200 + row*4 + l15] = acc[r] + bj;
      }
    }
  } else if (wid == 4){
    const int j = tid & 63;
    float a0=0.f, a1=0.f;
    #pragma unroll 4
    for (int k=0;k<128;++k){
      const float gk = geb[k];
      a0 += gk*vw1[k*128 + j];
      a1 += gk*vw1[k*128 + j + 64];
    }
    vh1[j]      = lrelu(a0 + vb1[j],    0.01f);
    vh1[j + 64] = lrelu(a1 + vb1[j+64], 0.01f);
    asm volatile("s_waitcnt lgkmcnt(0)" ::: "memory");
    __builtin_amdgcn_sched_barrier(0);
    float c0=0.f, c1=0.f;
    #pragma unroll 4
    for (int k=0;k<128;++k){
      const float hk = vh1[k];
      c0 += hk*vw2[k*128 + j];
      c1 += hk*vw2[k*128 + j + 64];
    }
    const float va = lrelu(c0 + vb2[j],    0.01f);
    const float vb = lrelu(c1 + vb2[j+64], 0.01f);
    float p = va*vw3[j] + vb*vw3[j+64];
    #pragma unroll
    for (int off=32; off>0; off>>=1) p += __shfl_down(p, off);
    if (j == 0) out_val[b] = p + vb3[0];
  }
}

extern "C" void kernel_launch(void* const* d_in, const int* in_sizes, int n_in,
                              void* d_out, int out_size, void* d_ws, size_t ws_size,
                              hipStream_t stream)
{
  const float* state = (const float*)d_in[0];
  const float* w1    = (const float*)d_in[1];
  const float* as1   = (const float*)d_in[2];
  const float* ad1   = (const float*)d_in[3];
  const float* b1_   = (const float*)d_in[4];
  const float* w2    = (const float*)d_in[5];
  const float* as2   = (const float*)d_in[6];
  const float* ad2   = (const float*)d_in[7];
  const float* b2_   = (const float*)d_in[8];
  const float* aw1   = (const float*)d_in[9];
  const float* ab1   = (const float*)d_in[10];
  const float* aw2   = (const float*)d_in[11];
  const float* ab2   = (const float*)d_in[12];
  const float* aw3   = (const float*)d_in[13];
  const float* ab3   = (const float*)d_in[14];
  const float* vw1   = (const float*)d_in[15];
  const float* vb1   = (const float*)d_in[16];
  const float* vw2   = (const float*)d_in[17];
  const float* vb2   = (const float*)d_in[18];
  const float* vw3   = (const float*)d_in[19];
  const float* vb3   = (const float*)d_in[20];

  const int B = in_sizes[0] / (NNODE * 64);   // 2048
  float* out_mean = (float*)d_out;
  float* out_val  = out_mean + (size_t)B * 200;
  u16* ws = (u16*)d_ws;

  ac_prep<<<128, 256, 0, stream>>>(w1, as1, ad1, w2, as2, ad2, aw1, aw2, aw3, ws);
  ac_main<<<B, NT, 0, stream>>>(state, b1_, b2_, ab1, ab2, ab3,
                                vw1, vb1, vw2, vb2, vw3, vb3,
                                ws, out_mean, out_val);
}

// Round 6
// 145.850 us; speedup vs baseline: 1.0788x; 1.0788x over previous
//
#include <hip/hip_runtime.h>

#define DI __device__ __forceinline__

typedef unsigned int uint32;
typedef unsigned short u16;
typedef __attribute__((ext_vector_type(8))) short s8v;   // 8 bf16 (4 VGPR)
typedef __attribute__((ext_vector_type(4))) float f4v;   // MFMA accumulator

DI float lrelu(float x, float s){ return x > 0.f ? x : s*x; }
DI u16 f2bu(float f){ uint32 u = __float_as_uint(f); return (u16)((u + 0x7FFFu + ((u>>16)&1u)) >> 16); }
DI float fastrcp(float x){ float r; asm("v_rcp_f32 %0, %1" : "=v"(r) : "v"(x)); return r; }

// branch-free gelu (erf via Abramowitz-Stegun 7.1.26, |eps|<=1.5e-7)
DI float gelu_f(float x){
  const float z = fabsf(x) * 0.70710678118654752f;
  const float t = fastrcp(1.f + 0.3275911f*z);
  float p = 1.061405429f;
  p = p*t - 1.453152027f;
  p = p*t + 1.421413741f;
  p = p*t - 0.284496736f;
  p = p*t + 0.254829592f;
  p = p*t;
  const float e = __expf(-z*z);
  float er = 1.f - p*e;
  er = copysignf(er, x);
  return 0.5f*x*(1.f + er);
}

DI f4v mfma16(s8v a, s8v b, f4v c){
  return __builtin_amdgcn_mfma_f32_16x16x32_bf16(a, b, c, 0, 0, 0);
}

constexpr int NNODE = 50;
constexpr int NT = 512;
constexpr int SCS = 134;     // sc row stride (f32); cols 128/129 = es/ed, 130..132 = wL/wS/wR

// d_ws layout (u16 units):
constexpr int WS1  = 0;       // per-head [144][64]: rows 0..127 = W1^T head h, 128=es fold, 129=ed fold
constexpr int WS2  = 18432;   // [144][256]: rows 0..127 = W2^T, 128=es2 fold, 129=ed2 fold
constexpr int WSA1 = 55296;   // aw1^T [128][128]
constexpr int WSA2 = 71680;   // aw2^T [128][128]
constexpr int WSA3 = 88064;   // aw3^T padded [16][128] (rows 4..15 zero)
constexpr int WSTOT= 90112;   // * 2 bytes

__global__ __launch_bounds__(256)
void ac_prep(const float* __restrict__ w1, const float* __restrict__ as1, const float* __restrict__ ad1,
             const float* __restrict__ w2, const float* __restrict__ as2, const float* __restrict__ ad2,
             const float* __restrict__ aw1, const float* __restrict__ aw2, const float* __restrict__ aw3,
             u16* __restrict__ ws)
{
  const int T1 = 2*144*64, T2 = 144*256, T3 = 128*128;
  for (int t = blockIdx.x*blockDim.x + threadIdx.x; t < WSTOT; t += gridDim.x*blockDim.x){
    float v; int o;
    if (t < T1){
      int h = t / 9216, r = t - h*9216, n = r>>6, k = r&63;
      if (n < 128) v = w1[k*256 + h*128 + n];
      else if (n < 130){
        const float* av = ((n==129) ? ad1 : as1) + h*128;
        const float* wr = w1 + k*256 + h*128;
        float s = 0.f;
        for (int c=0;c<128;++c) s += wr[c]*av[c];
        v = s;
      } else v = 0.f;
      o = WS1 + h*9216 + n*64 + k;
    } else if (t < T1+T2){
      int j = t - T1, n = j>>8, k = j&255;
      if (n < 128) v = w2[k*128 + n];
      else if (n < 130){
        const float* av = (n==129) ? ad2 : as2;
        const float* wr = w2 + k*128;
        float s = 0.f;
        for (int c=0;c<128;++c) s += wr[c]*av[c];
        v = s;
      } else v = 0.f;
      o = WS2 + n*256 + k;
    } else if (t < T1+T2+T3){
      int j = t - T1 - T2, n = j>>7, k = j&127;
      v = aw1[k*128 + n];
      o = WSA1 + n*128 + k;
    } else if (t < T1+T2+2*T3){
      int j = t - T1 - T2 - T3, n = j>>7, k = j&127;
      v = aw2[k*128 + n];
      o = WSA2 + n*128 + k;
    } else {
      int j = t - T1 - T2 - 2*T3, m = j>>7, k = j&127;
      v = (m < 4) ? aw3[k*4 + m] : 0.f;
      o = WSA3 + m*128 + k;
    }
    ws[o] = f2bu(v);
  }
}

// LDS map (f32 words), total 18816 f = 75.26 KB -> 2 blocks/CU:
//  sc   [64][134] f32 @ 0
//  Abuf bf16 16384 u16 @ 8576   (A2 [64][256] ; A3/A5 [64][128] first half, A4 second half)
//  As   bf16 4096 u16  @ 16768  (state tile; dead after fragment load -> overlay geb4 etc.)
//  geb4 [4][128] @ 16768 ; geb @ 17280 ; vh1 @ 17408

__global__ __launch_bounds__(NT)
void ac_main(const float* __restrict__ state,
             const float* __restrict__ b1, const float* __restrict__ b2,
             const float* __restrict__ ab1, const float* __restrict__ ab2,
             const float* __restrict__ ab3,
             const float* __restrict__ vw1, const float* __restrict__ vb1,
             const float* __restrict__ vw2, const float* __restrict__ vb2,
             const float* __restrict__ vw3, const float* __restrict__ vb3,
             const u16* __restrict__ ws,
             float* __restrict__ out_mean, float* __restrict__ out_val)
{
  __shared__ __align__(16) float sm[18816];
  float* sc   = sm;
  u16*   pAb  = (u16*)(sm + 8576);
  u16*   pAb2 = pAb + 8192;
  u16*   pAs  = (u16*)(sm + 16768);
  float* geb4 = sm + 16768;   // overlays As (dead after fragment preload)
  float* geb  = sm + 17280;
  float* vh1  = sm + 17408;

  const int tid = threadIdx.x, b = blockIdx.x;
  const int wid = tid>>6, l15 = tid&15, g = (tid>>4)&3;

  // ---- P0: pack state -> As bf16 [64][64], XOR-swizzled, rows 50..63 zero ----
  {
    const float4* xb4 = (const float4*)(state + (size_t)b * (NNODE*64));
    for (int t = tid; t < 800; t += NT){
      float4 v = xb4[t];
      int i = t>>4, k0 = (t&15)*4;
      ushort4 u;
      u.x = f2bu(v.x); u.y = f2bu(v.y); u.z = f2bu(v.z); u.w = f2bu(v.w);
      *(ushort4*)(pAs + i*64 + (k0 ^ ((i&7)<<3))) = u;
    }
    for (int t = tid; t < 224; t += NT){
      int i = 50 + (t>>4), k0 = (t&15)*4;
      *(ushort4*)(pAs + i*64 + (k0 ^ ((i&7)<<3))) = (ushort4){0,0,0,0};
    }
  }
  __syncthreads();

  // ---- G1 + attention1, per head ----
  {
    s8v aS[4][2];
    #pragma unroll
    for (int mt=0;mt<4;++mt)
      #pragma unroll
      for (int ks=0;ks<2;++ks){
        int row = mt*16 + l15, c = ks*32 + g*8;
        aS[mt][ks] = *(const s8v*)(pAs + row*64 + (c ^ ((row&7)<<3)));
      }

    for (int h=0; h<2; ++h){
      // G1 head h: C[64][130] -> sc (cols 0..127 features, 128=es, 129=ed)
      for (int nt = wid; nt < 9; nt += 8){
        f4v acc[4];
        #pragma unroll
        for (int mt=0;mt<4;++mt) acc[mt] = (f4v){0.f,0.f,0.f,0.f};
        #pragma unroll
        for (int ks=0;ks<2;++ks){
          s8v bf = *(const s8v*)(ws + WS1 + h*9216 + (nt*16 + l15)*64 + ks*32 + g*8);
          #pragma unroll
          for (int mt=0;mt<4;++mt) acc[mt] = mfma16(aS[mt][ks], bf, acc[mt]);
        }
        const int col = nt*16 + l15;
        if (col < 130){
          #pragma unroll
          for (int mt=0;mt<4;++mt){
            const int r0 = mt*16 + g*4;
            #pragma unroll
            for (int r=0;r<4;++r) sc[(r0+r)*SCS + col] = acc[mt][r];
          }
        }
      }
      __syncthreads();

      // per-row normalized stencil weights (redundant per wave; benign same-value races)
      {
        const int i = tid & 63;
        if (i < NNODE){
          const float edi = sc[i*SCS + 129];
          const float eS = __expf(lrelu(sc[i*SCS + 128] + edi, 0.2f));
          const float eL = (i > 0)       ? __expf(lrelu(sc[(i-1)*SCS + 128] + edi, 0.2f)) : 0.f;
          const float eR = (i < NNODE-1) ? __expf(lrelu(sc[(i+1)*SCS + 128] + edi, 0.2f)) : 0.f;
          const float rs = fastrcp(eL + eS + eR);
          sc[i*SCS + 130] = eL*rs;
          sc[i*SCS + 131] = eS*rs;
          sc[i*SCS + 132] = eR*rs;
        }
      }
      // cells: 4 row-strips x 128 cols, rotating feature registers
      {
        const int q = tid>>7, j = tid&127, jj = h*128 + j;
        const int i0 = q*13, i1 = (i0+13 < NNODE) ? i0+13 : NNODE;
        const float bj = b1[jj];
        float pv  = (i0 > 0) ? sc[(i0-1)*SCS + j] : 0.f;
        float cur = sc[i0*SCS + j];
        #pragma unroll 4
        for (int i = i0; i < i1; ++i){
          const float nx = (i < NNODE-1) ? sc[(i+1)*SCS + j] : 0.f;
          const float wL = sc[i*SCS + 130], wS = sc[i*SCS + 131], wR = sc[i*SCS + 132];
          const float v = gelu_f(wL*pv + wS*cur + wR*nx + bj);
          pAb[i*256 + (jj ^ ((i&7)<<3))] = f2bu(v);
          pv = cur; cur = nx;
        }
      }
      __syncthreads();
    }
  }

  // ---- G2: C[64][130] = A2[64x256] x W2x^T -> sc ----
  for (int nt = wid; nt < 9; nt += 8){
    f4v acc[4];
    #pragma unroll
    for (int mt=0;mt<4;++mt) acc[mt] = (f4v){0.f,0.f,0.f,0.f};
    #pragma unroll
    for (int ks=0;ks<8;++ks){
      s8v bf = *(const s8v*)(ws + WS2 + (nt*16 + l15)*256 + ks*32 + g*8);
      #pragma unroll
      for (int mt=0;mt<4;++mt){
        const int row = mt*16 + l15, c = ks*32 + g*8;
        s8v a = *(const s8v*)(pAb + row*256 + (c ^ ((row&7)<<3)));
        acc[mt] = mfma16(a, bf, acc[mt]);
      }
    }
    const int col = nt*16 + l15;
    if (col < 130){
      #pragma unroll
      for (int mt=0;mt<4;++mt){
        const int r0 = mt*16 + g*4;
        #pragma unroll
        for (int r=0;r<4;++r) sc[(r0+r)*SCS + col] = acc[mt][r];
      }
    }
  }
  __syncthreads();

  // ---- attention2: weights then cells ; GELU -> A3 bf16 [64][128] ; pool partials ----
  {
    const int i = tid & 63;
    if (i < NNODE){
      const float edi = sc[i*SCS + 129];
      const float eS = __expf(lrelu(sc[i*SCS + 128] + edi, 0.2f));
      const float eL = (i > 0)       ? __expf(lrelu(sc[(i-1)*SCS + 128] + edi, 0.2f)) : 0.f;
      const float eR = (i < NNODE-1) ? __expf(lrelu(sc[(i+1)*SCS + 128] + edi, 0.2f)) : 0.f;
      const float rs = fastrcp(eL + eS + eR);
      sc[i*SCS + 130] = eL*rs;
      sc[i*SCS + 131] = eS*rs;
      sc[i*SCS + 132] = eR*rs;
    }
  }
  {
    const int q = tid>>7, j = tid&127;
    const int i0 = q*13, i1 = (i0+13 < NNODE) ? i0+13 : NNODE;
    const float bj = b2[j];
    float ps = 0.f;
    float pv  = (i0 > 0) ? sc[(i0-1)*SCS + j] : 0.f;
    float cur = sc[i0*SCS + j];
    #pragma unroll 4
    for (int i = i0; i < i1; ++i){
      const float nx = (i < NNODE-1) ? sc[(i+1)*SCS + j] : 0.f;
      const float wL = sc[i*SCS + 130], wS = sc[i*SCS + 131], wR = sc[i*SCS + 132];
      const float v = gelu_f(wL*pv + wS*cur + wR*nx + bj);
      pAb[i*128 + (j ^ ((i&7)<<3))] = f2bu(v);
      ps += v;
      pv = cur; cur = nx;
    }
    geb4[q*128 + j] = ps;
  }
  __syncthreads();

  // ---- G3: C = A3 x aw1^T ; fused lrelu+pack -> A4 ; geb finalize ----
  {
    const int nt = wid;
    f4v acc[4];
    #pragma unroll
    for (int mt=0;mt<4;++mt) acc[mt] = (f4v){0.f,0.f,0.f,0.f};
    #pragma unroll
    for (int ks=0;ks<4;++ks){
      s8v bf = *(const s8v*)(ws + WSA1 + (nt*16 + l15)*128 + ks*32 + g*8);
      #pragma unroll
      for (int mt=0;mt<4;++mt){
        const int row = mt*16 + l15, c = ks*32 + g*8;
        s8v a = *(const s8v*)(pAb + row*128 + (c ^ ((row&7)<<3)));
        acc[mt] = mfma16(a, bf, acc[mt]);
      }
    }
    const int col = nt*16 + l15;
    const float bj = ab1[col];
    #pragma unroll
    for (int mt=0;mt<4;++mt){
      #pragma unroll
      for (int r=0;r<4;++r){
        const int row = mt*16 + g*4 + r;
        const float v = lrelu(acc[mt][r] + bj, 0.01f);
        pAb2[row*128 + (col ^ ((row&7)<<3))] = f2bu(v);
      }
    }
    if (tid < 128)
      geb[tid] = (geb4[tid] + geb4[128+tid] + geb4[256+tid] + geb4[384+tid]) * 0.02f;
  }
  __syncthreads();

  // ---- G4: C = A4 x aw2^T ; fused lrelu(+ab2)+pack -> A5 (A3 region, dead) ----
  {
    const int nt = wid;
    f4v acc[4];
    #pragma unroll
    for (int mt=0;mt<4;++mt) acc[mt] = (f4v){0.f,0.f,0.f,0.f};
    #pragma unroll
    for (int ks=0;ks<4;++ks){
      s8v bf = *(const s8v*)(ws + WSA2 + (nt*16 + l15)*128 + ks*32 + g*8);
      #pragma unroll
      for (int mt=0;mt<4;++mt){
        const int row = mt*16 + l15, c = ks*32 + g*8;
        s8v a = *(const s8v*)(pAb2 + row*128 + (c ^ ((row&7)<<3)));
        acc[mt] = mfma16(a, bf, acc[mt]);
      }
    }
    const int col = nt*16 + l15;
    const float bj = ab2[col];
    #pragma unroll
    for (int mt=0;mt<4;++mt){
      #pragma unroll
      for (int r=0;r<4;++r){
        const int row = mt*16 + g*4 + r;
        const float v = lrelu(acc[mt][r] + bj, 0.01f);
        pAb[row*128 + (col ^ ((row&7)<<3))] = f2bu(v);
      }
    }
  }
  __syncthreads();

  // ---- G5: actor L3 via tiny MFMA (waves 0-3) ; value MLP (wave 4). No more barriers. ----
  if (wid < 4){
    const int mt = wid;
    f4v acc = (f4v){0.f,0.f,0.f,0.f};
    #pragma unroll
    for (int ks=0;ks<4;++ks){
      s8v bf = *(const s8v*)(ws + WSA3 + l15*128 + ks*32 + g*8);
      const int row = mt*16 + l15, c = ks*32 + g*8;
      s8v a = *(const s8v*)(pAb + row*128 + (c ^ ((row&7)<<3)));
      acc = mfma16(a, bf, acc);
    }
    if (l15 < 4){
      const float bj = ab3[l15];
      #pragma unroll
      for (int r=0;r<4;++r){
        const int row = mt*16 + g*4 + r;
        if (row < NNODE) out_mean[(size_t)b*200 + row*4 + l15] = acc[r] + bj;
      }
    }
  } else if (wid == 4){
    const int j = tid & 63;
    float a0=0.f, a1=0.f;
    #pragma unroll 4
    for (int k=0;k<128;++k){
      const float gk = geb[k];
      a0 += gk*vw1[k*128 + j];
      a1 += gk*vw1[k*128 + j + 64];
    }
    vh1[j]      = lrelu(a0 + vb1[j],    0.01f);
    vh1[j + 64] = lrelu(a1 + vb1[j+64], 0.01f);
    asm volatile("s_waitcnt lgkmcnt(0)" ::: "memory");
    __builtin_amdgcn_sched_barrier(0);
    float c0=0.f, c1=0.f;
    #pragma unroll 4
    for (int k=0;k<128;++k){
      const float hk = vh1[k];
      c0 += hk*vw2[k*128 + j];
      c1 += hk*vw2[k*128 + j + 64];
    }
    const float va = lrelu(c0 + vb2[j],    0.01f);
    const float vb = lrelu(c1 + vb2[j+64], 0.01f);
    float p = va*vw3[j] + vb*vw3[j+64];
    #pragma unroll
    for (int off=32; off>0; off>>=1) p += __shfl_down(p, off);
    if (j == 0) out_val[b] = p + vb3[0];
  }
}

extern "C" void kernel_launch(void* const* d_in, const int* in_sizes, int n_in,
                              void* d_out, int out_size, void* d_ws, size_t ws_size,
                              hipStream_t stream)
{
  const float* state = (const float*)d_in[0];
  const float* w1    = (const float*)d_in[1];
  const float* as1   = (const float*)d_in[2];
  const float* ad1   = (const float*)d_in[3];
  const float* b1_   = (const float*)d_in[4];
  const float* w2    = (const float*)d_in[5];
  const float* as2   = (const float*)d_in[6];
  const float* ad2   = (const float*)d_in[7];
  const float* b2_   = (const float*)d_in[8];
  const float* aw1   = (const float*)d_in[9];
  const float* ab1   = (const float*)d_in[10];
  const float* aw2   = (const float*)d_in[11];
  const float* ab2   = (const float*)d_in[12];
  const float* aw3   = (const float*)d_in[13];
  const float* ab3   = (const float*)d_in[14];
  const float* vw1   = (const float*)d_in[15];
  const float* vb1   = (const float*)d_in[16];
  const float* vw2   = (const float*)d_in[17];
  const float* vb2   = (const float*)d_in[18];
  const float* vw3   = (const float*)d_in[19];
  const float* vb3   = (const float*)d_in[20];

  const int B = in_sizes[0] / (NNODE * 64);   // 2048
  float* out_mean = (float*)d_out;
  float* out_val  = out_mean + (size_t)B * 200;
  u16* ws = (u16*)d_ws;

  ac_prep<<<128, 256, 0, stream>>>(w1, as1, ad1, w2, as2, ad2, aw1, aw2, aw3, ws);
  ac_main<<<B, NT, 0, stream>>>(state, b1_, b2_, ab1, ab2, ab3,
                                vw1, vb1, vw2, vb2, vw3, vb3,
                                ws, out_mean, out_val);
}